// Round 3
// baseline (674.439 us; speedup 1.0000x reference)
//
#include <hip/hip_runtime.h>
#include <cstdint>
#include <cstddef>

#define B_SZ 16384
#define X_D  64
#define U_D  16
#define Z_D  32
#define H_D  1024
#define A_D  256
#define DT_C 0.02f

typedef _Float16 f16;
typedef f16   f16x8 __attribute__((ext_vector_type(8)));
typedef f16   f16x4 __attribute__((ext_vector_type(4)));
typedef float f32x4 __attribute__((ext_vector_type(4)));

#define AS1 __attribute__((address_space(1)))
#define AS3 __attribute__((address_space(3)))

__device__ __forceinline__ void gld_lds16(const void* g, void* l) {
    __builtin_amdgcn_global_load_lds((AS1 void*)(g), (AS3 void*)(l), 16, 0, 0);
}

struct GArg {
    const f16*  A;     // [M, lda] activations (row-major subview)
    const f16*  W;     // [N, K]   transposed weights, ld == K
    const float* bias; // [N]
    void*       C;     // output
    const float* U;    // u input (OM==2)
    const float* zf;   // encoder latent (OM==2)
    const float* aux;  // aux output (OM==2)
    int lda, ldc, K;
};
struct GPair { GArg g[2]; };

// ---------------------------------------------------------------------------
// f16 MFMA GEMM: C = act(A @ W^T + bias).
// OM 0: scalar f32 store.
// OM 1: f16 out via LDS repack + dwordx4 (requires BM=256, BN=128, WM=2).
// OM 2: fused Bu contraction + Koopman rotation -> znb f16 [M,32].
// blockIdx.z selects p.g[z] (pair same-shape GEMMs in one launch).
// ---------------------------------------------------------------------------
template<int BM,int BN,int BK,int WM,int WN,bool SILU,int OM>
__launch_bounds__(256)
__global__ void gemm_k(GPair p)
{
    static_assert(OM != 1 || (BM == 256 && BN == 128 && WM == 2), "OM1 shape");
    const GArg ga = p.g[blockIdx.z];

    constexpr int SEGROW = BK / 8;
    constexpr int SMASK  = (SEGROW < 8 ? SEGROW : 8) - 1;
    constexpr int WTM = BM / WM, WTN = BN / WN;
    constexpr int RM = WTM / 16, RN = WTN / 16;
    constexpr int ITA = (BM * SEGROW) / 256;
    constexpr int ITB = (BN * SEGROW) / 256;

    constexpr int STAGE_B = (BM + BN) * BK * 2;
    constexpr int CS_B    = (OM == 1) ? 128 * BN * 2 : 0;
    constexpr int SMEM_B  = STAGE_B > CS_B ? STAGE_B : CS_B;
    __shared__ __align__(16) char smem[SMEM_B];
    f16* As = (f16*)smem;
    f16* Bs = As + BM * BK;

    const int tid  = threadIdx.x;
    const int lane = tid & 63;
    const int wave = tid >> 6;
    const int wm = wave / WN, wn = wave % WN;
    const int l15 = lane & 15, quad = lane >> 4;

    const size_t arow0 = (size_t)blockIdx.x * BM;
    const size_t brow0 = (size_t)blockIdx.y * BN;
    const int lda = ga.lda, K = ga.K;

    f32x4 zero = {0.f, 0.f, 0.f, 0.f};
    f32x4 acc[RM][RN];
#pragma unroll
    for (int i = 0; i < RM; ++i)
#pragma unroll
        for (int j = 0; j < RN; ++j) acc[i][j] = zero;

    for (int k0 = 0; k0 < K; k0 += BK) {
#pragma unroll
        for (int it = 0; it < ITA; ++it) {
            int s = it * 256 + tid;
            int row = s / SEGROW, st = s % SEGROW;
            int sg = st ^ (row & SMASK);
            gld_lds16(ga.A + (arow0 + row) * lda + k0 + sg * 8, &As[s * 8]);
        }
#pragma unroll
        for (int it = 0; it < ITB; ++it) {
            int s = it * 256 + tid;
            int row = s / SEGROW, st = s % SEGROW;
            int sg = st ^ (row & SMASK);
            gld_lds16(ga.W + (brow0 + row) * K + k0 + sg * 8, &Bs[s * 8]);
        }
        __syncthreads();

#pragma unroll
        for (int kk = 0; kk < BK; kk += 32) {
            f16x8 af[RM], bf[RN];
#pragma unroll
            for (int i = 0; i < RM; ++i) {
                int row = wm * WTM + i * 16 + l15;
                int st  = ((kk >> 3) + quad) ^ (row & SMASK);
                af[i] = *(const f16x8*)&As[(row * SEGROW + st) * 8];
            }
#pragma unroll
            for (int j = 0; j < RN; ++j) {
                int row = wn * WTN + j * 16 + l15;
                int st  = ((kk >> 3) + quad) ^ (row & SMASK);
                bf[j] = *(const f16x8*)&Bs[(row * SEGROW + st) * 8];
            }
#pragma unroll
            for (int i = 0; i < RM; ++i)
#pragma unroll
                for (int j = 0; j < RN; ++j)
                    acc[i][j] = __builtin_amdgcn_mfma_f32_16x16x32_f16(
                        af[i], bf[j], acc[i][j], 0, 0, 0);
        }
        __syncthreads();
    }

    const int rowbL = wm * WTM;
    const int colbL = wn * WTN;

    if constexpr (OM == 2) {
        // Bu[row,z] = sum_u (acc+bias)[row, z*16+u] * U[row,u]; u == l15.
        // Then Koopman: znb = zf + DT*(Az + Bu), Az from aux rotation.
        const int zcol0 = ((int)brow0 + colbL) >> 4;
#pragma unroll
        for (int i = 0; i < RM; ++i) {
#pragma unroll
            for (int r = 0; r < 4; ++r) {
                int row = (int)arow0 + rowbL + i * 16 + quad * 4 + r;
                float uv = ga.U[row * 16 + l15];
#pragma unroll
                for (int j = 0; j < RN; ++j) {
                    int col = (int)brow0 + colbL + j * 16 + l15;
                    float v = (acc[i][j][r] + ga.bias[col]) * uv;
                    v += __shfl_xor(v, 8, 16);
                    v += __shfl_xor(v, 4, 16);
                    v += __shfl_xor(v, 2, 16);
                    v += __shfl_xor(v, 1, 16);
                    if (l15 == 0) {
                        int z = zcol0 + j;
                        int pb = row * 32 + (z & ~1);
                        float a  = ga.aux[pb], b = ga.aux[pb + 1];
                        float z0 = ga.zf[pb],  z1 = ga.zf[pb + 1];
                        float f  = __expf(a * DT_C);
                        float c_ = __cosf(b * DT_C);
                        float s_ = __sinf(b * DT_C);
                        float Az = (z & 1) ? f * (s_ * z0 + c_ * z1)
                                           : f * (c_ * z0 - s_ * z1);
                        float zc = (z & 1) ? z1 : z0;
                        ((f16*)ga.C)[row * 32 + z] = (f16)(zc + DT_C * (Az + v));
                    }
                }
            }
        }
    } else if constexpr (OM == 1) {
        // Two passes of 128 rows through a 32 KB repack buffer.
        f16* Cs = (f16*)smem;
        f16* Cout = (f16*)ga.C;
#pragma unroll
        for (int pass = 0; pass < 2; ++pass) {
            if (wm == pass) {
#pragma unroll
                for (int j = 0; j < RN; ++j) {
                    int colL = wn * WTN + j * 16 + l15;
                    float bv = ga.bias[(int)brow0 + colL];
                    int chL = colL >> 3, wi = colL & 7;
#pragma unroll
                    for (int i = 0; i < RM; ++i) {
#pragma unroll
                        for (int r = 0; r < 4; ++r) {
                            int rowL = i * 16 + quad * 4 + r;
                            float v = acc[i][j][r] + bv;
                            if (SILU) v = v / (1.0f + __expf(-v));
                            Cs[rowL * BN + ((chL ^ (rowL & 15)) << 3) + wi] = (f16)v;
                        }
                    }
                }
            }
            __syncthreads();
#pragma unroll
            for (int it = 0; it < (128 * BN / 8) / 256; ++it) {
                int s = it * 256 + tid;
                int rowL = s >> 4, ch = s & 15;
                f16x8 v = *(const f16x8*)&Cs[rowL * BN + ((ch ^ (rowL & 15)) << 3)];
                *(f16x8*)&Cout[(size_t)(arow0 + pass * 128 + rowL) * ga.ldc
                               + brow0 + ch * 8] = v;
            }
            __syncthreads();
        }
    } else {
        float* Cout = (float*)ga.C;
#pragma unroll
        for (int j = 0; j < RN; ++j) {
            int col = (int)brow0 + colbL + j * 16 + l15;
            float bv = ga.bias[col];
#pragma unroll
            for (int i = 0; i < RM; ++i) {
#pragma unroll
                for (int r = 0; r < 4; ++r) {
                    int row = (int)arow0 + rowbL + i * 16 + quad * 4 + r;
                    float v = acc[i][j][r] + bv;
                    if (SILU) v = v / (1.0f + __expf(-v));
                    Cout[(size_t)row * ga.ldc + col] = v;
                }
            }
        }
    }
}

// ---------------------------------------------------------------------------
// One-shot prep: 13 weight transposes (f32 [K,N] -> f16 [N,K]), x f32->f16,
// L1 bias concat. One launch.
// ---------------------------------------------------------------------------
struct PrepArgs {
    const float* w[13];
    f16*         wt[13];
    int          K[13];
    int          N[13];
    const float* bsrc[3];
    float*       bias1;
    const float* x;
    f16*         xb;
};

__launch_bounds__(256)
__global__ void prep_k(PrepArgs pa, int ntrans, int ncvt)
{
    int bid = blockIdx.x;
    if (bid < ntrans) {
        int i = 0, t;
        for (;; ++i) {
            t = (pa.K[i] >> 5) * (pa.N[i] >> 5);
            if (bid < t) break;
            bid -= t;
        }
        const int K = pa.K[i], N = pa.N[i];
        const int tn = N >> 5;
        const int k0 = (bid / tn) << 5, n0 = (bid % tn) << 5;
        __shared__ float tbuf[32][33];
        const int tx = threadIdx.x & 31, ty = threadIdx.x >> 5;
        const float* src = pa.w[i];
        f16* dst = pa.wt[i];
#pragma unroll
        for (int r = 0; r < 32; r += 8)
            tbuf[ty + r][tx] = src[(size_t)(k0 + ty + r) * N + n0 + tx];
        __syncthreads();
#pragma unroll
        for (int r = 0; r < 32; r += 8)
            dst[(size_t)(n0 + ty + r) * K + k0 + tx] = (f16)tbuf[tx][ty + r];
    } else if (bid < ntrans + ncvt) {
        int i = ((bid - ntrans) * 256 + threadIdx.x) * 4;
        float4 v = *(const float4*)(pa.x + i);
        f16x4 o = {(f16)v.x, (f16)v.y, (f16)v.z, (f16)v.w};
        *(f16x4*)(pa.xb + i) = o;
    } else {
        int idx = (bid - ntrans - ncvt) * 256 + (int)threadIdx.x; // 0..1535
        float v = (idx < 1024) ? pa.bsrc[0][idx]
                : (idx < 1280) ? pa.bsrc[1][idx - 1024]
                               : pa.bsrc[2][idx - 1280];
        pa.bias1[idx] = v;
    }
}

extern "C" void kernel_launch(void* const* d_in, const int* in_sizes, int n_in,
                              void* d_out, int out_size, void* d_ws, size_t ws_size,
                              hipStream_t stream)
{
    (void)in_sizes; (void)n_in; (void)out_size; (void)ws_size;
    const float* x    = (const float*)d_in[0];
    const float* u    = (const float*)d_in[1];
    const float* e_w1 = (const float*)d_in[2];  const float* e_b1 = (const float*)d_in[3];
    const float* e_w2 = (const float*)d_in[4];  const float* e_b2 = (const float*)d_in[5];
    const float* e_w3 = (const float*)d_in[6];  const float* e_b3 = (const float*)d_in[7];
    const float* d_w1 = (const float*)d_in[8];  const float* d_b1 = (const float*)d_in[9];
    const float* d_w2 = (const float*)d_in[10]; const float* d_b2 = (const float*)d_in[11];
    const float* d_w3 = (const float*)d_in[12]; const float* d_b3 = (const float*)d_in[13];
    const float* d_w4 = (const float*)d_in[14]; const float* d_b4 = (const float*)d_in[15];
    const float* a_w1 = (const float*)d_in[16]; const float* a_b1 = (const float*)d_in[17];
    const float* a_w2 = (const float*)d_in[18]; const float* a_b2 = (const float*)d_in[19];
    const float* a_w3 = (const float*)d_in[20]; const float* a_b3 = (const float*)d_in[21];
    const float* b_w1 = (const float*)d_in[22]; const float* b_b1 = (const float*)d_in[23];
    const float* b_w2 = (const float*)d_in[24]; const float* b_b2 = (const float*)d_in[25];
    const float* b_w3 = (const float*)d_in[26]; const float* b_b3 = (const float*)d_in[27];

    char* p = (char*)d_ws;
    auto alloc = [&](size_t nbytes) -> void* {
        void* r = (void*)p;
        p += (nbytes + 255) & ~(size_t)255;
        return r;
    };
    // activations
    f16*   xb   = (f16*)  alloc((size_t)B_SZ * X_D * 2);
    f16*   cc1  = (f16*)  alloc((size_t)B_SZ * 1536 * 2);  // h1e | p1a | p1b
    f16*   cc2  = (f16*)  alloc((size_t)B_SZ * 1536 * 2);  // h2e | p2a | p2b
    float* zf   = (float*)alloc((size_t)B_SZ * Z_D * 4);
    float* auxf = (float*)alloc((size_t)B_SZ * Z_D * 4);
    f16*   znb  = (f16*)  alloc((size_t)B_SZ * Z_D * 2);
    // decoder ping-pong aliases (cc1/cc2 dead by then)
    f16*   h1d  = cc1;
    f16*   h2d  = cc2;
    f16*   h3d  = cc1;
    // transposed f16 weights [N][K]
    f16*   W1t   = (f16*)alloc((size_t)1536 * X_D * 2);    // e|a|b layer-1 stacked
    float* bias1 = (float*)alloc(1536 * 4);
    f16* e_w2t = (f16*)alloc((size_t)H_D * H_D * 2);
    f16* e_w3t = (f16*)alloc((size_t)Z_D * H_D * 2);
    f16* d_w1t = (f16*)alloc((size_t)H_D * Z_D * 2);
    f16* d_w2t = (f16*)alloc((size_t)H_D * H_D * 2);
    f16* d_w3t = (f16*)alloc((size_t)H_D * H_D * 2);
    f16* d_w4t = (f16*)alloc((size_t)X_D * H_D * 2);
    f16* a_w2t = (f16*)alloc((size_t)A_D * A_D * 2);
    f16* a_w3t = (f16*)alloc((size_t)Z_D * A_D * 2);
    f16* b_w2t = (f16*)alloc((size_t)A_D * A_D * 2);
    f16* b_w3t = (f16*)alloc((size_t)(Z_D * U_D) * A_D * 2);

    // ---- prep ----
    PrepArgs pa;
    const float* ws_[13] = {e_w1, e_w2, e_w3, d_w1, d_w2, d_w3, d_w4,
                            a_w1, a_w2, a_w3, b_w1, b_w2, b_w3};
    f16* wts_[13] = {W1t, e_w2t, e_w3t, d_w1t, d_w2t, d_w3t, d_w4t,
                     W1t + (size_t)1024 * X_D, a_w2t, a_w3t,
                     W1t + (size_t)1280 * X_D, b_w2t, b_w3t};
    int Ks_[13] = {X_D, H_D, H_D, Z_D, H_D, H_D, H_D, X_D, A_D, A_D, X_D, A_D, A_D};
    int Ns_[13] = {H_D, H_D, Z_D, H_D, H_D, H_D, X_D, A_D, A_D, Z_D, A_D, A_D, Z_D*U_D};
    int ntrans = 0;
    for (int i = 0; i < 13; ++i) {
        pa.w[i] = ws_[i]; pa.wt[i] = wts_[i]; pa.K[i] = Ks_[i]; pa.N[i] = Ns_[i];
        ntrans += (Ks_[i] >> 5) * (Ns_[i] >> 5);
    }
    pa.bsrc[0] = e_b1; pa.bsrc[1] = a_b1; pa.bsrc[2] = b_b1;
    pa.bias1 = bias1; pa.x = x; pa.xb = xb;
    const int ncvt = (B_SZ * X_D) / 1024;
    prep_k<<<ntrans + ncvt + 6, 256, 0, stream>>>(pa, ntrans, ncvt);

    auto G = [](const f16* A, const f16* W, const float* bias, void* C,
                int lda, int ldc, int K, const float* U = nullptr,
                const float* zf_ = nullptr, const float* aux_ = nullptr) {
        GArg g; g.A = A; g.W = W; g.bias = bias; g.C = C; g.U = U;
        g.zf = zf_; g.aux = aux_; g.lda = lda; g.ldc = ldc; g.K = K; return g;
    };
    GPair pr;

    // ---- fused layer-1: [B,64] @ [64,1536] -> cc1 ----
    pr.g[0] = pr.g[1] = G(xb, W1t, bias1, cc1, X_D, 1536, X_D);
    gemm_k<256,128,64,2,2,true,1><<<dim3(B_SZ/256, 1536/128, 1), 256, 0, stream>>>(pr);

    // ---- encoder layer-2 ----
    pr.g[0] = pr.g[1] = G(cc1, e_w2t, e_b2, cc2, 1536, 1536, H_D);
    gemm_k<256,128,64,2,2,true,1><<<dim3(B_SZ/256, H_D/128, 1), 256, 0, stream>>>(pr);

    // ---- aux/bnet layer-2 (paired) ----
    pr.g[0] = G(cc1 + 1024, a_w2t, a_b2, cc2 + 1024, 1536, 1536, A_D);
    pr.g[1] = G(cc1 + 1280, b_w2t, b_b2, cc2 + 1280, 1536, 1536, A_D);
    gemm_k<256,128,64,2,2,true,1><<<dim3(B_SZ/256, A_D/128, 2), 256, 0, stream>>>(pr);

    // ---- encoder/aux layer-3 (paired) -> zf, auxf ----
    pr.g[0] = G(cc2,        e_w3t, e_b3, zf,   1536, Z_D, H_D);
    pr.g[1] = G(cc2 + 1024, a_w3t, a_b3, auxf, 1536, Z_D, A_D);
    gemm_k<64,32,64,4,1,false,0><<<dim3(B_SZ/64, 1, 2), 256, 0, stream>>>(pr);

    // ---- bnet layer-3 + fused Bu + Koopman -> znb ----
    pr.g[0] = pr.g[1] = G(cc2 + 1280, b_w3t, b_b3, znb, 1536, Z_D, A_D, u, zf, auxf);
    gemm_k<256,128,64,2,2,false,2><<<dim3(B_SZ/256, (Z_D*U_D)/128, 1), 256, 0, stream>>>(pr);

    // ---- decoder ----
    pr.g[0] = pr.g[1] = G(znb, d_w1t, d_b1, h1d, Z_D, H_D, Z_D);
    gemm_k<256,128,32,2,2,true,1><<<dim3(B_SZ/256, H_D/128, 1), 256, 0, stream>>>(pr);

    pr.g[0] = pr.g[1] = G(h1d, d_w2t, d_b2, h2d, H_D, H_D, H_D);
    gemm_k<256,128,64,2,2,true,1><<<dim3(B_SZ/256, H_D/128, 1), 256, 0, stream>>>(pr);

    pr.g[0] = pr.g[1] = G(h2d, d_w3t, d_b3, h3d, H_D, H_D, H_D);
    gemm_k<256,128,64,2,2,true,1><<<dim3(B_SZ/256, H_D/128, 1), 256, 0, stream>>>(pr);

    pr.g[0] = pr.g[1] = G(h3d, d_w4t, d_b4, d_out, H_D, X_D, H_D);
    gemm_k<64,64,64,2,2,false,0><<<dim3(B_SZ/64, 1, 1), 256, 0, stream>>>(pr);
}

// Round 4
// 370.868 us; speedup vs baseline: 1.8185x; 1.8185x over previous
//
#include <hip/hip_runtime.h>
#include <cstdint>
#include <cstddef>

#define B_SZ 16384
#define X_D  64
#define U_D  16
#define Z_D  32
#define H_D  1024
#define A_D  256
#define DT_C 0.02f

typedef _Float16 f16;
typedef f16   f16x8 __attribute__((ext_vector_type(8)));
typedef f16   f16x4 __attribute__((ext_vector_type(4)));
typedef float f32x4 __attribute__((ext_vector_type(4)));

#define AS1 __attribute__((address_space(1)))
#define AS3 __attribute__((address_space(3)))

__device__ __forceinline__ void gld_lds16(const void* g, void* l) {
    __builtin_amdgcn_global_load_lds((AS1 void*)(g), (AS3 void*)(l), 16, 0, 0);
}

struct GArg {
    const f16*  A;     // [M, lda] activations (row-major subview)
    const f16*  W;     // [N, K]   transposed weights, ld == K
    const float* bias; // [N]
    void*       C;     // output
    int lda, ldc, K;
};
// Up to 3 sub-GEMMs in one launch; yn[i] = #N-tiles of sub-GEMM i.
struct GSet { GArg g[3]; int yn0, yn1; };

// ---------------------------------------------------------------------------
// f16 MFMA GEMM: C = act(A @ W^T + bias). 128x128x64 proven config (R2).
// OM 0: scalar f32 store.  OM 1: f16 out via LDS repack + dwordx4 (BN=128).
// ---------------------------------------------------------------------------
template<int BM,int BN,int BK,int WM,int WN,bool SILU,int OM>
__launch_bounds__(256)
__global__ void gemm_k(GSet p)
{
    static_assert(OM != 1 || BN == 128, "OM1 repack assumes BN=128");
    int yb = blockIdx.y, gi = 0;
    if (yb >= p.yn0) { yb -= p.yn0; gi = 1; if (yb >= p.yn1) { yb -= p.yn1; gi = 2; } }
    const GArg ga = p.g[gi];

    constexpr int SEGROW = BK / 8;
    constexpr int SMASK  = (SEGROW < 8 ? SEGROW : 8) - 1;
    constexpr int WTM = BM / WM, WTN = BN / WN;
    constexpr int RM = WTM / 16, RN = WTN / 16;
    constexpr int ITA = (BM * SEGROW) / 256;
    constexpr int ITB = (BN * SEGROW) / 256;

    constexpr int STAGE_B = (BM + BN) * BK * 2;
    constexpr int CS_B    = (OM == 1) ? BM * BN * 2 : 0;
    constexpr int SMEM_B  = STAGE_B > CS_B ? STAGE_B : CS_B;
    __shared__ __align__(16) char smem[SMEM_B];
    f16* As = (f16*)smem;
    f16* Bs = As + BM * BK;

    const int tid  = threadIdx.x;
    const int lane = tid & 63;
    const int wave = tid >> 6;
    const int wm = wave / WN, wn = wave % WN;
    const int l15 = lane & 15, quad = lane >> 4;

    const size_t arow0 = (size_t)blockIdx.x * BM;
    const size_t brow0 = (size_t)yb * BN;
    const int lda = ga.lda, K = ga.K;

    f32x4 zero = {0.f, 0.f, 0.f, 0.f};
    f32x4 acc[RM][RN];
#pragma unroll
    for (int i = 0; i < RM; ++i)
#pragma unroll
        for (int j = 0; j < RN; ++j) acc[i][j] = zero;

    for (int k0 = 0; k0 < K; k0 += BK) {
#pragma unroll
        for (int it = 0; it < ITA; ++it) {
            int s = it * 256 + tid;
            int row = s / SEGROW, st = s % SEGROW;
            int sg = st ^ (row & SMASK);
            gld_lds16(ga.A + (arow0 + row) * lda + k0 + sg * 8, &As[s * 8]);
        }
#pragma unroll
        for (int it = 0; it < ITB; ++it) {
            int s = it * 256 + tid;
            int row = s / SEGROW, st = s % SEGROW;
            int sg = st ^ (row & SMASK);
            gld_lds16(ga.W + (brow0 + row) * K + k0 + sg * 8, &Bs[s * 8]);
        }
        __syncthreads();

#pragma unroll
        for (int kk = 0; kk < BK; kk += 32) {
            f16x8 af[RM], bf[RN];
#pragma unroll
            for (int i = 0; i < RM; ++i) {
                int row = wm * WTM + i * 16 + l15;
                int st  = ((kk >> 3) + quad) ^ (row & SMASK);
                af[i] = *(const f16x8*)&As[(row * SEGROW + st) * 8];
            }
#pragma unroll
            for (int j = 0; j < RN; ++j) {
                int row = wn * WTN + j * 16 + l15;
                int st  = ((kk >> 3) + quad) ^ (row & SMASK);
                bf[j] = *(const f16x8*)&Bs[(row * SEGROW + st) * 8];
            }
#pragma unroll
            for (int i = 0; i < RM; ++i)
#pragma unroll
                for (int j = 0; j < RN; ++j)
                    acc[i][j] = __builtin_amdgcn_mfma_f32_16x16x32_f16(
                        af[i], bf[j], acc[i][j], 0, 0, 0);
        }
        __syncthreads();
    }

    const int rowbL = wm * WTM;
    const int colbL = wn * WTN;

    if constexpr (OM == 1) {
        f16* Cs = (f16*)smem;   // safe: loop-trailing barrier already passed
#pragma unroll
        for (int j = 0; j < RN; ++j) {
            int colL = colbL + j * 16 + l15;
            float bv = ga.bias[(int)brow0 + colL];
            int chL = colL >> 3, wi = colL & 7;
#pragma unroll
            for (int i = 0; i < RM; ++i) {
#pragma unroll
                for (int r = 0; r < 4; ++r) {
                    int rowL = rowbL + i * 16 + quad * 4 + r;
                    float v = acc[i][j][r] + bv;
                    if (SILU) v = v / (1.0f + __expf(-v));
                    Cs[rowL * BN + ((chL ^ (rowL & 15)) << 3) + wi] = (f16)v;
                }
            }
        }
        __syncthreads();
        f16* Cout = (f16*)ga.C;
#pragma unroll
        for (int pass = 0; pass < (BM * BN / 8) / 256; ++pass) {
            int s = pass * 256 + tid;
            int rowL = s >> 4;          // BN/8 == 16 chunks per row
            int ch = s & 15;
            f16x8 v = *(const f16x8*)&Cs[rowL * BN + ((ch ^ (rowL & 15)) << 3)];
            *(f16x8*)&Cout[(size_t)(arow0 + rowL) * ga.ldc + brow0 + ch * 8] = v;
        }
    } else {
        float* Cout = (float*)ga.C;
#pragma unroll
        for (int j = 0; j < RN; ++j) {
            int col = (int)brow0 + colbL + j * 16 + l15;
            float bv = ga.bias[col];
#pragma unroll
            for (int i = 0; i < RM; ++i) {
#pragma unroll
                for (int r = 0; r < 4; ++r) {
                    int row = (int)arow0 + rowbL + i * 16 + quad * 4 + r;
                    float v = acc[i][j][r] + bv;
                    if (SILU) v = v / (1.0f + __expf(-v));
                    Cout[(size_t)row * ga.ldc + col] = v;
                }
            }
        }
    }
}

// ---------------------------------------------------------------------------
// Fused middle: e3 + a3 + b3 + Bu contraction + Koopman -> znb [B,32] f16.
// One block = 32 rows. All latent state (z, aux, Bu) lives in LDS.
// ---------------------------------------------------------------------------
__launch_bounds__(256)
__global__ void mid_k(const f16* __restrict__ cc2,
                      const f16* __restrict__ e_w3t, const float* __restrict__ e_b3,
                      const f16* __restrict__ a_w3t, const float* __restrict__ a_b3,
                      const f16* __restrict__ b_w3t, const float* __restrict__ b_b3,
                      const float* __restrict__ u,   f16* __restrict__ znb)
{
    __shared__ __align__(16) f16 As[32 * 64];
    __shared__ __align__(16) f16 Bs[128 * 64];
    __shared__ float zb[32 * 32];
    __shared__ float ab[32 * 32];
    __shared__ float bu[32 * 32];
    __shared__ float ub[32 * 16];

    const int tid  = threadIdx.x;
    const int lane = tid & 63, wave = tid >> 6;
    const int l15 = lane & 15, quad = lane >> 4;
    const int r0 = blockIdx.x * 32;

    ub[tid]       = u[r0 * 16 + tid];
    ub[tid + 256] = u[r0 * 16 + 256 + tid];

    // ---- phases E (z = enc-L3) and A (aux) : N=32 ----
#pragma unroll 1
    for (int ph = 0; ph < 2; ++ph) {
        const f16* W    = ph ? a_w3t : e_w3t;
        const float* bs = ph ? a_b3 : e_b3;
        const int K     = ph ? 256 : 1024;
        const int co    = ph ? 1024 : 0;
        float* ob       = ph ? ab : zb;
        f32x4 acc = {0.f, 0.f, 0.f, 0.f};
        for (int k0 = 0; k0 < K; k0 += 64) {
            {   // stage A 32x64 (1 seg/thread)
                int row = tid >> 3, sg = (tid & 7) ^ (row & 7);
                gld_lds16(cc2 + (size_t)(r0 + row) * 1536 + co + k0 + sg * 8,
                          &As[tid * 8]);
            }
            {   // stage W 32x64
                int row = tid >> 3, sg = (tid & 7) ^ (row & 7);
                gld_lds16(W + (size_t)row * K + k0 + sg * 8, &Bs[tid * 8]);
            }
            __syncthreads();
#pragma unroll
            for (int kk = 0; kk < 64; kk += 32) {
                int ar = ((wave >> 1) << 4) + l15;
                int ast = ((kk >> 3) + quad) ^ (ar & 7);
                f16x8 af = *(const f16x8*)&As[(ar * 8 + ast) * 8];
                int br = ((wave & 1) << 4) + l15;
                int bst = ((kk >> 3) + quad) ^ (br & 7);
                f16x8 bf = *(const f16x8*)&Bs[(br * 8 + bst) * 8];
                acc = __builtin_amdgcn_mfma_f32_16x16x32_f16(af, bf, acc, 0, 0, 0);
            }
            __syncthreads();
        }
#pragma unroll
        for (int r = 0; r < 4; ++r) {
            int row = ((wave >> 1) << 4) + quad * 4 + r;
            int col = ((wave & 1) << 4) + l15;
            ob[row * 32 + col] = acc[r] + bs[col];
        }
    }

    // ---- phase B: b3 (N=512, K=256) in 4 col-chunks of 128 + Bu ----
#pragma unroll 1
    for (int ch = 0; ch < 4; ++ch) {
        f32x4 acc[2][2];
#pragma unroll
        for (int i = 0; i < 2; ++i)
#pragma unroll
            for (int j = 0; j < 2; ++j) acc[i][j] = f32x4{0.f, 0.f, 0.f, 0.f};
        for (int k0 = 0; k0 < 256; k0 += 64) {
            {   int row = tid >> 3, sg = (tid & 7) ^ (row & 7);
                gld_lds16(cc2 + (size_t)(r0 + row) * 1536 + 1280 + k0 + sg * 8,
                          &As[tid * 8]);
            }
#pragma unroll
            for (int it = 0; it < 4; ++it) {
                int s = it * 256 + tid;
                int row = s >> 3, sg = (s & 7) ^ (row & 7);
                gld_lds16(b_w3t + (size_t)(ch * 128 + row) * 256 + k0 + sg * 8,
                          &Bs[s * 8]);
            }
            __syncthreads();
#pragma unroll
            for (int kk = 0; kk < 64; kk += 32) {
                f16x8 af[2], bf[2];
#pragma unroll
                for (int i = 0; i < 2; ++i) {
                    int ar = i * 16 + l15;
                    int st = ((kk >> 3) + quad) ^ (ar & 7);
                    af[i] = *(const f16x8*)&As[(ar * 8 + st) * 8];
                }
#pragma unroll
                for (int j = 0; j < 2; ++j) {
                    int br = wave * 32 + j * 16 + l15;
                    int st = ((kk >> 3) + quad) ^ (br & 7);
                    bf[j] = *(const f16x8*)&Bs[(br * 8 + st) * 8];
                }
#pragma unroll
                for (int i = 0; i < 2; ++i)
#pragma unroll
                    for (int j = 0; j < 2; ++j)
                        acc[i][j] = __builtin_amdgcn_mfma_f32_16x16x32_f16(
                            af[i], bf[j], acc[i][j], 0, 0, 0);
            }
            __syncthreads();
        }
        // Bu: col = ch*128 + wave*32 + j*16 + u (u = l15); z = col >> 4
#pragma unroll
        for (int j = 0; j < 2; ++j) {
            int colg = ch * 128 + wave * 32 + j * 16 + l15;
            float bv = b_b3[colg];
            int z = colg >> 4;
#pragma unroll
            for (int i = 0; i < 2; ++i) {
#pragma unroll
                for (int r = 0; r < 4; ++r) {
                    int row = i * 16 + quad * 4 + r;
                    float v = (acc[i][j][r] + bv) * ub[row * 16 + l15];
                    v += __shfl_xor(v, 8, 16);
                    v += __shfl_xor(v, 4, 16);
                    v += __shfl_xor(v, 2, 16);
                    v += __shfl_xor(v, 1, 16);
                    if (l15 == 0) bu[row * 32 + z] = v;
                }
            }
        }
    }
    __syncthreads();

    // ---- phase K: Koopman rotation -> znb ----
#pragma unroll
    for (int t = 0; t < 4; ++t) {
        int idx = t * 256 + tid;
        int row = idx >> 5, z = idx & 31;
        int pb = idx & ~1;
        float a  = ab[pb], b = ab[pb + 1];
        float z0 = zb[pb], z1 = zb[pb + 1];
        float f  = __expf(a * DT_C);
        float c_ = __cosf(b * DT_C);
        float s_ = __sinf(b * DT_C);
        float Az = (z & 1) ? f * (s_ * z0 + c_ * z1) : f * (c_ * z0 - s_ * z1);
        float zc = (z & 1) ? z1 : z0;
        znb[(size_t)(r0 + row) * 32 + z] = (f16)(zc + DT_C * (Az + bu[idx]));
    }
}

// ---------------------------------------------------------------------------
// One-shot prep: 13 weight transposes (f32 [K,N] -> f16 [N,K]), x f32->f16,
// L1 bias concat.
// ---------------------------------------------------------------------------
struct PrepArgs {
    const float* w[13];
    f16*         wt[13];
    int          K[13];
    int          N[13];
    const float* bsrc[3];
    float*       bias1;
    const float* x;
    f16*         xb;
};

__launch_bounds__(256)
__global__ void prep_k(PrepArgs pa, int ntrans, int ncvt)
{
    int bid = blockIdx.x;
    if (bid < ntrans) {
        int i = 0, t;
        for (;; ++i) {
            t = (pa.K[i] >> 5) * (pa.N[i] >> 5);
            if (bid < t) break;
            bid -= t;
        }
        const int K = pa.K[i], N = pa.N[i];
        const int tn = N >> 5;
        const int k0 = (bid / tn) << 5, n0 = (bid % tn) << 5;
        __shared__ float tbuf[32][33];
        const int tx = threadIdx.x & 31, ty = threadIdx.x >> 5;
        const float* src = pa.w[i];
        f16* dst = pa.wt[i];
#pragma unroll
        for (int r = 0; r < 32; r += 8)
            tbuf[ty + r][tx] = src[(size_t)(k0 + ty + r) * N + n0 + tx];
        __syncthreads();
#pragma unroll
        for (int r = 0; r < 32; r += 8)
            dst[(size_t)(n0 + ty + r) * K + k0 + tx] = (f16)tbuf[tx][ty + r];
    } else if (bid < ntrans + ncvt) {
        int i = ((bid - ntrans) * 256 + threadIdx.x) * 4;
        float4 v = *(const float4*)(pa.x + i);
        f16x4 o = {(f16)v.x, (f16)v.y, (f16)v.z, (f16)v.w};
        *(f16x4*)(pa.xb + i) = o;
    } else {
        int idx = (bid - ntrans - ncvt) * 256 + (int)threadIdx.x; // 0..1535
        float v = (idx < 1024) ? pa.bsrc[0][idx]
                : (idx < 1280) ? pa.bsrc[1][idx - 1024]
                               : pa.bsrc[2][idx - 1280];
        pa.bias1[idx] = v;
    }
}

extern "C" void kernel_launch(void* const* d_in, const int* in_sizes, int n_in,
                              void* d_out, int out_size, void* d_ws, size_t ws_size,
                              hipStream_t stream)
{
    (void)in_sizes; (void)n_in; (void)out_size; (void)ws_size;
    const float* x    = (const float*)d_in[0];
    const float* u    = (const float*)d_in[1];
    const float* e_w1 = (const float*)d_in[2];  const float* e_b1 = (const float*)d_in[3];
    const float* e_w2 = (const float*)d_in[4];  const float* e_b2 = (const float*)d_in[5];
    const float* e_w3 = (const float*)d_in[6];  const float* e_b3 = (const float*)d_in[7];
    const float* d_w1 = (const float*)d_in[8];  const float* d_b1 = (const float*)d_in[9];
    const float* d_w2 = (const float*)d_in[10]; const float* d_b2 = (const float*)d_in[11];
    const float* d_w3 = (const float*)d_in[12]; const float* d_b3 = (const float*)d_in[13];
    const float* d_w4 = (const float*)d_in[14]; const float* d_b4 = (const float*)d_in[15];
    const float* a_w1 = (const float*)d_in[16]; const float* a_b1 = (const float*)d_in[17];
    const float* a_w2 = (const float*)d_in[18]; const float* a_b2 = (const float*)d_in[19];
    const float* a_w3 = (const float*)d_in[20]; const float* a_b3 = (const float*)d_in[21];
    const float* b_w1 = (const float*)d_in[22]; const float* b_b1 = (const float*)d_in[23];
    const float* b_w2 = (const float*)d_in[24]; const float* b_b2 = (const float*)d_in[25];
    const float* b_w3 = (const float*)d_in[26]; const float* b_b3 = (const float*)d_in[27];

    char* p = (char*)d_ws;
    auto alloc = [&](size_t nbytes) -> void* {
        void* r = (void*)p;
        p += (nbytes + 255) & ~(size_t)255;
        return r;
    };
    // activations
    f16*   xb   = (f16*)  alloc((size_t)B_SZ * X_D * 2);
    f16*   cc1  = (f16*)  alloc((size_t)B_SZ * 1536 * 2);  // h1e | p1a | p1b
    f16*   cc2  = (f16*)  alloc((size_t)B_SZ * 1536 * 2);  // h2e | p2a | p2b
    f16*   znb  = (f16*)  alloc((size_t)B_SZ * Z_D * 2);
    // decoder ping-pong aliases (cc1/cc2 dead by then)
    f16*   h1d  = cc1;
    f16*   h2d  = cc2;
    f16*   h3d  = cc1;
    // transposed f16 weights [N][K]
    f16*   W1t   = (f16*)alloc((size_t)1536 * X_D * 2);    // e|a|b layer-1 stacked
    float* bias1 = (float*)alloc(1536 * 4);
    f16* e_w2t = (f16*)alloc((size_t)H_D * H_D * 2);
    f16* e_w3t = (f16*)alloc((size_t)Z_D * H_D * 2);
    f16* d_w1t = (f16*)alloc((size_t)H_D * Z_D * 2);
    f16* d_w2t = (f16*)alloc((size_t)H_D * H_D * 2);
    f16* d_w3t = (f16*)alloc((size_t)H_D * H_D * 2);
    f16* d_w4t = (f16*)alloc((size_t)X_D * H_D * 2);
    f16* a_w2t = (f16*)alloc((size_t)A_D * A_D * 2);
    f16* a_w3t = (f16*)alloc((size_t)Z_D * A_D * 2);
    f16* b_w2t = (f16*)alloc((size_t)A_D * A_D * 2);
    f16* b_w3t = (f16*)alloc((size_t)(Z_D * U_D) * A_D * 2);

    // ---- prep ----
    PrepArgs pa;
    const float* ws_[13] = {e_w1, e_w2, e_w3, d_w1, d_w2, d_w3, d_w4,
                            a_w1, a_w2, a_w3, b_w1, b_w2, b_w3};
    f16* wts_[13] = {W1t, e_w2t, e_w3t, d_w1t, d_w2t, d_w3t, d_w4t,
                     W1t + (size_t)1024 * X_D, a_w2t, a_w3t,
                     W1t + (size_t)1280 * X_D, b_w2t, b_w3t};
    int Ks_[13] = {X_D, H_D, H_D, Z_D, H_D, H_D, H_D, X_D, A_D, A_D, X_D, A_D, A_D};
    int Ns_[13] = {H_D, H_D, Z_D, H_D, H_D, H_D, X_D, A_D, A_D, Z_D, A_D, A_D, Z_D*U_D};
    int ntrans = 0;
    for (int i = 0; i < 13; ++i) {
        pa.w[i] = ws_[i]; pa.wt[i] = wts_[i]; pa.K[i] = Ks_[i]; pa.N[i] = Ns_[i];
        ntrans += (Ks_[i] >> 5) * (Ns_[i] >> 5);
    }
    pa.bsrc[0] = e_b1; pa.bsrc[1] = a_b1; pa.bsrc[2] = b_b1;
    pa.bias1 = bias1; pa.x = x; pa.xb = xb;
    const int ncvt = (B_SZ * X_D) / 1024;
    prep_k<<<ntrans + ncvt + 6, 256, 0, stream>>>(pa, ntrans, ncvt);

    auto G = [](const f16* A, const f16* W, const float* bias, void* C,
                int lda, int ldc, int K) {
        GArg g; g.A = A; g.W = W; g.bias = bias; g.C = C;
        g.lda = lda; g.ldc = ldc; g.K = K; return g;
    };
    GSet s;

    // ---- fused layer-1: [B,64] @ [64,1536] -> cc1 ----
    s.g[0] = G(xb, W1t, bias1, cc1, X_D, 1536, X_D);
    s.yn0 = 12; s.yn1 = 0;
    gemm_k<128,128,64,2,2,true,1><<<dim3(B_SZ/128, 12), 256, 0, stream>>>(s);

    // ---- merged layer-2: e2 (8 tiles) + a2 (2) + b2 (2), one launch ----
    s.g[0] = G(cc1,        e_w2t, e_b2, cc2,        1536, 1536, H_D);
    s.g[1] = G(cc1 + 1024, a_w2t, a_b2, cc2 + 1024, 1536, 1536, A_D);
    s.g[2] = G(cc1 + 1280, b_w2t, b_b2, cc2 + 1280, 1536, 1536, A_D);
    s.yn0 = 8; s.yn1 = 2;
    gemm_k<128,128,64,2,2,true,1><<<dim3(B_SZ/128, 12), 256, 0, stream>>>(s);

    // ---- fused middle: e3+a3+b3+Bu+Koopman -> znb ----
    mid_k<<<B_SZ/32, 256, 0, stream>>>(cc2, e_w3t, e_b3, a_w3t, a_b3,
                                       b_w3t, b_b3, u, znb);

    // ---- decoder ----
    s.yn0 = 8; s.yn1 = 0;
    s.g[0] = G(znb, d_w1t, d_b1, h1d, Z_D, H_D, Z_D);
    gemm_k<128,128,32,2,2,true,1><<<dim3(B_SZ/128, 8), 256, 0, stream>>>(s);

    s.g[0] = G(h1d, d_w2t, d_b2, h2d, H_D, H_D, H_D);
    gemm_k<128,128,64,2,2,true,1><<<dim3(B_SZ/128, 8), 256, 0, stream>>>(s);

    s.g[0] = G(h2d, d_w3t, d_b3, h3d, H_D, H_D, H_D);
    gemm_k<128,128,64,2,2,true,1><<<dim3(B_SZ/128, 8), 256, 0, stream>>>(s);

    s.g[0] = G(h3d, d_w4t, d_b4, d_out, H_D, X_D, H_D);
    s.yn0 = 1;
    gemm_k<64,64,64,2,2,false,0><<<dim3(B_SZ/64, 1), 256, 0, stream>>>(s);
}

// Round 5
// 365.027 us; speedup vs baseline: 1.8476x; 1.0160x over previous
//
#include <hip/hip_runtime.h>
#include <cstdint>
#include <cstddef>

#define B_SZ 16384
#define X_D  64
#define U_D  16
#define Z_D  32
#define H_D  1024
#define A_D  256
#define DT_C 0.02f

typedef _Float16 f16;
typedef f16   f16x8 __attribute__((ext_vector_type(8)));
typedef f16   f16x4 __attribute__((ext_vector_type(4)));
typedef float f32x4 __attribute__((ext_vector_type(4)));
typedef float f32x16 __attribute__((ext_vector_type(16)));

#define AS1 __attribute__((address_space(1)))
#define AS3 __attribute__((address_space(3)))

__device__ __forceinline__ void gld_lds16(const void* g, void* l) {
    __builtin_amdgcn_global_load_lds((AS1 void*)(g), (AS3 void*)(l), 16, 0, 0);
}

struct GArg {
    const f16*  A;     // [M, lda] activations (row-major subview)
    const f16*  W;     // [N, K]   transposed weights, ld == K
    const float* bias; // [N]
    void*       C;     // output
    int lda, ldc, K;
};
// Up to 3 sub-GEMMs in one launch; yn0/yn1 = #N-tiles of sub-GEMM 0/1.
struct GSet { GArg g[3]; int yn0, yn1; };

// ---------------------------------------------------------------------------
// f16 MFMA GEMM: C = act(A @ W^T + bias). 128x128x64 block (5 blocks/CU),
// 32x32x16 MFMA (half the MFMA issue slots of 16x16x32, 15% higher ceiling).
// Staging via global_load_lds(16B), XOR segment swizzle; staging pointers
// hoisted out of the K-loop (increment by BK).
// OM 0: scalar f32 store.  OM 1: f16 out via LDS repack + dwordx4 (BN=128).
// ---------------------------------------------------------------------------
template<int BM,int BN,int BK,int WM,int WN,bool SILU,int OM>
__launch_bounds__(256)
__global__ void gemm_k(GSet p)
{
    static_assert(OM != 1 || BN == 128, "OM1 repack assumes BN=128");
    int yb = blockIdx.y, gi = 0;
    if (yb >= p.yn0) { yb -= p.yn0; gi = 1; if (yb >= p.yn1) { yb -= p.yn1; gi = 2; } }
    const GArg ga = p.g[gi];

    constexpr int SEGROW = BK / 8;
    constexpr int SMASK  = (SEGROW < 8 ? SEGROW : 8) - 1;
    constexpr int WTM = BM / WM, WTN = BN / WN;
    static_assert(WTM % 32 == 0 && WTN % 32 == 0, "wave tile in 32x32 units");
    constexpr int RM = WTM / 32, RN = WTN / 32;
    constexpr int KS = BK / 16;                 // 32x32x16 k-steps per K-tile
    constexpr int ITA = (BM * SEGROW) / 256;
    constexpr int ITB = (BN * SEGROW) / 256;

    constexpr int STAGE_B = (BM + BN) * BK * 2;
    constexpr int CS_B    = (OM == 1) ? BM * BN * 2 : 0;
    constexpr int SMEM_B  = STAGE_B > CS_B ? STAGE_B : CS_B;
    __shared__ __align__(16) char smem[SMEM_B];
    f16* As = (f16*)smem;
    f16* Bs = As + BM * BK;

    const int tid  = threadIdx.x;
    const int lane = tid & 63;
    const int wave = tid >> 6;
    const int wm = wave / WN, wn = wave % WN;
    const int l31 = lane & 31, half = lane >> 5;

    const size_t arow0 = (size_t)blockIdx.x * BM;
    const size_t brow0 = (size_t)yb * BN;
    const int lda = ga.lda, K = ga.K;

    // Hoisted staging pointers: one per global_load_lds, advanced by BK/iter.
    const f16* aptr[ITA];
    const f16* bptr[ITB];
#pragma unroll
    for (int it = 0; it < ITA; ++it) {
        int s = it * 256 + tid;
        int row = s / SEGROW, st = s % SEGROW;
        int sg = st ^ (row & SMASK);
        aptr[it] = ga.A + (arow0 + row) * lda + sg * 8;
    }
#pragma unroll
    for (int it = 0; it < ITB; ++it) {
        int s = it * 256 + tid;
        int row = s / SEGROW, st = s % SEGROW;
        int sg = st ^ (row & SMASK);
        bptr[it] = ga.W + (brow0 + row) * K + sg * 8;
    }

    f32x16 acc[RM][RN];
#pragma unroll
    for (int i = 0; i < RM; ++i)
#pragma unroll
        for (int j = 0; j < RN; ++j)
#pragma unroll
            for (int r = 0; r < 16; ++r) acc[i][j][r] = 0.f;

    for (int k0 = 0; k0 < K; k0 += BK) {
#pragma unroll
        for (int it = 0; it < ITA; ++it) {
            gld_lds16(aptr[it], &As[(it * 256 + tid) * 8]);
            aptr[it] += BK;
        }
#pragma unroll
        for (int it = 0; it < ITB; ++it) {
            gld_lds16(bptr[it], &Bs[(it * 256 + tid) * 8]);
            bptr[it] += BK;
        }
        __syncthreads();

#pragma unroll
        for (int ks = 0; ks < KS; ++ks) {
            f16x8 af[RM], bf[RN];
#pragma unroll
            for (int i = 0; i < RM; ++i) {
                int row = wm * WTM + i * 32 + l31;
                int st  = (ks * 2 + half) ^ (row & SMASK);
                af[i] = *(const f16x8*)&As[(row * SEGROW + st) * 8];
            }
#pragma unroll
            for (int j = 0; j < RN; ++j) {
                int row = wn * WTN + j * 32 + l31;
                int st  = (ks * 2 + half) ^ (row & SMASK);
                bf[j] = *(const f16x8*)&Bs[(row * SEGROW + st) * 8];
            }
#pragma unroll
            for (int i = 0; i < RM; ++i)
#pragma unroll
                for (int j = 0; j < RN; ++j)
                    acc[i][j] = __builtin_amdgcn_mfma_f32_32x32x16_f16(
                        af[i], bf[j], acc[i][j], 0, 0, 0);
        }
        __syncthreads();
    }

    // C/D layout (32x32, m74/m101-verified): col = lane&31,
    // row = (reg&3) + 8*(reg>>2) + 4*(lane>>5)
    const int rowbL = wm * WTM;
    const int colbL = wn * WTN;

    if constexpr (OM == 1) {
        f16* Cs = (f16*)smem;   // safe: loop-trailing barrier already passed
#pragma unroll
        for (int j = 0; j < RN; ++j) {
            int colL = colbL + j * 32 + l31;
            float bv = ga.bias[(int)brow0 + colL];
            int chL = colL >> 3, wi = colL & 7;
#pragma unroll
            for (int i = 0; i < RM; ++i) {
#pragma unroll
                for (int r = 0; r < 16; ++r) {
                    int rowL = rowbL + i * 32 + (r & 3) + 8 * (r >> 2) + 4 * half;
                    float v = acc[i][j][r] + bv;
                    if (SILU) v = v / (1.0f + __expf(-v));
                    Cs[rowL * BN + ((chL ^ (rowL & 15)) << 3) + wi] = (f16)v;
                }
            }
        }
        __syncthreads();
        f16* Cout = (f16*)ga.C;
#pragma unroll
        for (int pass = 0; pass < (BM * BN / 8) / 256; ++pass) {
            int s = pass * 256 + tid;
            int rowL = s >> 4;          // BN/8 == 16 chunks per row
            int ch = s & 15;
            f16x8 v = *(const f16x8*)&Cs[rowL * BN + ((ch ^ (rowL & 15)) << 3)];
            *(f16x8*)&Cout[(size_t)(arow0 + rowL) * ga.ldc + brow0 + ch * 8] = v;
        }
    } else {
        float* Cout = (float*)ga.C;
#pragma unroll
        for (int j = 0; j < RN; ++j) {
            int col = (int)brow0 + colbL + j * 32 + l31;
            float bv = ga.bias[col];
#pragma unroll
            for (int i = 0; i < RM; ++i) {
#pragma unroll
                for (int r = 0; r < 16; ++r) {
                    int row = (int)arow0 + rowbL + i * 32
                            + (r & 3) + 8 * (r >> 2) + 4 * half;
                    float v = acc[i][j][r] + bv;
                    if (SILU) v = v / (1.0f + __expf(-v));
                    Cout[(size_t)row * ga.ldc + col] = v;
                }
            }
        }
    }
}

// ---------------------------------------------------------------------------
// Fused middle: e3 + a3 + b3 + Bu contraction + Koopman -> znb [B,32] f16.
// One block = 32 rows. All latent state (z, aux, Bu) lives in LDS.
// (16x16x32 MFMA path — verified in R4, untouched.)
// ---------------------------------------------------------------------------
__launch_bounds__(256)
__global__ void mid_k(const f16* __restrict__ cc2,
                      const f16* __restrict__ e_w3t, const float* __restrict__ e_b3,
                      const f16* __restrict__ a_w3t, const float* __restrict__ a_b3,
                      const f16* __restrict__ b_w3t, const float* __restrict__ b_b3,
                      const float* __restrict__ u,   f16* __restrict__ znb)
{
    __shared__ __align__(16) f16 As[32 * 64];
    __shared__ __align__(16) f16 Bs[128 * 64];
    __shared__ float zb[32 * 32];
    __shared__ float ab[32 * 32];
    __shared__ float bu[32 * 32];
    __shared__ float ub[32 * 16];

    const int tid  = threadIdx.x;
    const int lane = tid & 63, wave = tid >> 6;
    const int l15 = lane & 15, quad = lane >> 4;
    const int r0 = blockIdx.x * 32;

    ub[tid]       = u[r0 * 16 + tid];
    ub[tid + 256] = u[r0 * 16 + 256 + tid];

    // ---- phases E (z = enc-L3) and A (aux) : N=32 ----
#pragma unroll 1
    for (int ph = 0; ph < 2; ++ph) {
        const f16* W    = ph ? a_w3t : e_w3t;
        const float* bs = ph ? a_b3 : e_b3;
        const int K     = ph ? 256 : 1024;
        const int co    = ph ? 1024 : 0;
        float* ob       = ph ? ab : zb;
        f32x4 acc = {0.f, 0.f, 0.f, 0.f};
        for (int k0 = 0; k0 < K; k0 += 64) {
            {   // stage A 32x64 (1 seg/thread)
                int row = tid >> 3, sg = (tid & 7) ^ (row & 7);
                gld_lds16(cc2 + (size_t)(r0 + row) * 1536 + co + k0 + sg * 8,
                          &As[tid * 8]);
            }
            {   // stage W 32x64
                int row = tid >> 3, sg = (tid & 7) ^ (row & 7);
                gld_lds16(W + (size_t)row * K + k0 + sg * 8, &Bs[tid * 8]);
            }
            __syncthreads();
#pragma unroll
            for (int kk = 0; kk < 64; kk += 32) {
                int ar = ((wave >> 1) << 4) + l15;
                int ast = ((kk >> 3) + quad) ^ (ar & 7);
                f16x8 af = *(const f16x8*)&As[(ar * 8 + ast) * 8];
                int br = ((wave & 1) << 4) + l15;
                int bst = ((kk >> 3) + quad) ^ (br & 7);
                f16x8 bf = *(const f16x8*)&Bs[(br * 8 + bst) * 8];
                acc = __builtin_amdgcn_mfma_f32_16x16x32_f16(af, bf, acc, 0, 0, 0);
            }
            __syncthreads();
        }
#pragma unroll
        for (int r = 0; r < 4; ++r) {
            int row = ((wave >> 1) << 4) + quad * 4 + r;
            int col = ((wave & 1) << 4) + l15;
            ob[row * 32 + col] = acc[r] + bs[col];
        }
    }

    // ---- phase B: b3 (N=512, K=256) in 4 col-chunks of 128 + Bu ----
#pragma unroll 1
    for (int ch = 0; ch < 4; ++ch) {
        f32x4 acc[2][2];
#pragma unroll
        for (int i = 0; i < 2; ++i)
#pragma unroll
            for (int j = 0; j < 2; ++j) acc[i][j] = f32x4{0.f, 0.f, 0.f, 0.f};
        for (int k0 = 0; k0 < 256; k0 += 64) {
            {   int row = tid >> 3, sg = (tid & 7) ^ (row & 7);
                gld_lds16(cc2 + (size_t)(r0 + row) * 1536 + 1280 + k0 + sg * 8,
                          &As[tid * 8]);
            }
#pragma unroll
            for (int it = 0; it < 4; ++it) {
                int s = it * 256 + tid;
                int row = s >> 3, sg = (s & 7) ^ (row & 7);
                gld_lds16(b_w3t + (size_t)(ch * 128 + row) * 256 + k0 + sg * 8,
                          &Bs[s * 8]);
            }
            __syncthreads();
#pragma unroll
            for (int kk = 0; kk < 64; kk += 32) {
                f16x8 af[2], bf[2];
#pragma unroll
                for (int i = 0; i < 2; ++i) {
                    int ar = i * 16 + l15;
                    int st = ((kk >> 3) + quad) ^ (ar & 7);
                    af[i] = *(const f16x8*)&As[(ar * 8 + st) * 8];
                }
#pragma unroll
                for (int j = 0; j < 2; ++j) {
                    int br = wave * 32 + j * 16 + l15;
                    int st = ((kk >> 3) + quad) ^ (br & 7);
                    bf[j] = *(const f16x8*)&Bs[(br * 8 + st) * 8];
                }
#pragma unroll
                for (int i = 0; i < 2; ++i)
#pragma unroll
                    for (int j = 0; j < 2; ++j)
                        acc[i][j] = __builtin_amdgcn_mfma_f32_16x16x32_f16(
                            af[i], bf[j], acc[i][j], 0, 0, 0);
            }
            __syncthreads();
        }
        // Bu: col = ch*128 + wave*32 + j*16 + u (u = l15); z = col >> 4
#pragma unroll
        for (int j = 0; j < 2; ++j) {
            int colg = ch * 128 + wave * 32 + j * 16 + l15;
            float bv = b_b3[colg];
            int z = colg >> 4;
#pragma unroll
            for (int i = 0; i < 2; ++i) {
#pragma unroll
                for (int r = 0; r < 4; ++r) {
                    int row = i * 16 + quad * 4 + r;
                    float v = (acc[i][j][r] + bv) * ub[row * 16 + l15];
                    v += __shfl_xor(v, 8, 16);
                    v += __shfl_xor(v, 4, 16);
                    v += __shfl_xor(v, 2, 16);
                    v += __shfl_xor(v, 1, 16);
                    if (l15 == 0) bu[row * 32 + z] = v;
                }
            }
        }
    }
    __syncthreads();

    // ---- phase K: Koopman rotation -> znb ----
#pragma unroll
    for (int t = 0; t < 4; ++t) {
        int idx = t * 256 + tid;
        int row = idx >> 5, z = idx & 31;
        int pb = idx & ~1;
        float a  = ab[pb], b = ab[pb + 1];
        float z0 = zb[pb], z1 = zb[pb + 1];
        float f  = __expf(a * DT_C);
        float c_ = __cosf(b * DT_C);
        float s_ = __sinf(b * DT_C);
        float Az = (z & 1) ? f * (s_ * z0 + c_ * z1) : f * (c_ * z0 - s_ * z1);
        float zc = (z & 1) ? z1 : z0;
        znb[(size_t)(r0 + row) * 32 + z] = (f16)(zc + DT_C * (Az + bu[idx]));
    }
}

// ---------------------------------------------------------------------------
// One-shot prep: 13 weight transposes (f32 [K,N] -> f16 [N,K]), x f32->f16,
// L1 bias concat.
// ---------------------------------------------------------------------------
struct PrepArgs {
    const float* w[13];
    f16*         wt[13];
    int          K[13];
    int          N[13];
    const float* bsrc[3];
    float*       bias1;
    const float* x;
    f16*         xb;
};

__launch_bounds__(256)
__global__ void prep_k(PrepArgs pa, int ntrans, int ncvt)
{
    int bid = blockIdx.x;
    if (bid < ntrans) {
        int i = 0, t;
        for (;; ++i) {
            t = (pa.K[i] >> 5) * (pa.N[i] >> 5);
            if (bid < t) break;
            bid -= t;
        }
        const int K = pa.K[i], N = pa.N[i];
        const int tn = N >> 5;
        const int k0 = (bid / tn) << 5, n0 = (bid % tn) << 5;
        __shared__ float tbuf[32][33];
        const int tx = threadIdx.x & 31, ty = threadIdx.x >> 5;
        const float* src = pa.w[i];
        f16* dst = pa.wt[i];
#pragma unroll
        for (int r = 0; r < 32; r += 8)
            tbuf[ty + r][tx] = src[(size_t)(k0 + ty + r) * N + n0 + tx];
        __syncthreads();
#pragma unroll
        for (int r = 0; r < 32; r += 8)
            dst[(size_t)(n0 + ty + r) * K + k0 + tx] = (f16)tbuf[tx][ty + r];
    } else if (bid < ntrans + ncvt) {
        int i = ((bid - ntrans) * 256 + threadIdx.x) * 4;
        float4 v = *(const float4*)(pa.x + i);
        f16x4 o = {(f16)v.x, (f16)v.y, (f16)v.z, (f16)v.w};
        *(f16x4*)(pa.xb + i) = o;
    } else {
        int idx = (bid - ntrans - ncvt) * 256 + (int)threadIdx.x; // 0..1535
        float v = (idx < 1024) ? pa.bsrc[0][idx]
                : (idx < 1280) ? pa.bsrc[1][idx - 1024]
                               : pa.bsrc[2][idx - 1280];
        pa.bias1[idx] = v;
    }
}

extern "C" void kernel_launch(void* const* d_in, const int* in_sizes, int n_in,
                              void* d_out, int out_size, void* d_ws, size_t ws_size,
                              hipStream_t stream)
{
    (void)in_sizes; (void)n_in; (void)out_size; (void)ws_size;
    const float* x    = (const float*)d_in[0];
    const float* u    = (const float*)d_in[1];
    const float* e_w1 = (const float*)d_in[2];  const float* e_b1 = (const float*)d_in[3];
    const float* e_w2 = (const float*)d_in[4];  const float* e_b2 = (const float*)d_in[5];
    const float* e_w3 = (const float*)d_in[6];  const float* e_b3 = (const float*)d_in[7];
    const float* d_w1 = (const float*)d_in[8];  const float* d_b1 = (const float*)d_in[9];
    const float* d_w2 = (const float*)d_in[10]; const float* d_b2 = (const float*)d_in[11];
    const float* d_w3 = (const float*)d_in[12]; const float* d_b3 = (const float*)d_in[13];
    const float* d_w4 = (const float*)d_in[14]; const float* d_b4 = (const float*)d_in[15];
    const float* a_w1 = (const float*)d_in[16]; const float* a_b1 = (const float*)d_in[17];
    const float* a_w2 = (const float*)d_in[18]; const float* a_b2 = (const float*)d_in[19];
    const float* a_w3 = (const float*)d_in[20]; const float* a_b3 = (const float*)d_in[21];
    const float* b_w1 = (const float*)d_in[22]; const float* b_b1 = (const float*)d_in[23];
    const float* b_w2 = (const float*)d_in[24]; const float* b_b2 = (const float*)d_in[25];
    const float* b_w3 = (const float*)d_in[26]; const float* b_b3 = (const float*)d_in[27];

    char* p = (char*)d_ws;
    auto alloc = [&](size_t nbytes) -> void* {
        void* r = (void*)p;
        p += (nbytes + 255) & ~(size_t)255;
        return r;
    };
    // activations
    f16*   xb   = (f16*)  alloc((size_t)B_SZ * X_D * 2);
    f16*   cc1  = (f16*)  alloc((size_t)B_SZ * 1536 * 2);  // h1e | p1a | p1b
    f16*   cc2  = (f16*)  alloc((size_t)B_SZ * 1536 * 2);  // h2e | p2a | p2b
    f16*   znb  = (f16*)  alloc((size_t)B_SZ * Z_D * 2);
    // decoder ping-pong aliases (cc1/cc2 dead by then)
    f16*   h1d  = cc1;
    f16*   h2d  = cc2;
    f16*   h3d  = cc1;
    // transposed f16 weights [N][K]
    f16*   W1t   = (f16*)alloc((size_t)1536 * X_D * 2);    // e|a|b layer-1 stacked
    float* bias1 = (float*)alloc(1536 * 4);
    f16* e_w2t = (f16*)alloc((size_t)H_D * H_D * 2);
    f16* e_w3t = (f16*)alloc((size_t)Z_D * H_D * 2);
    f16* d_w1t = (f16*)alloc((size_t)H_D * Z_D * 2);
    f16* d_w2t = (f16*)alloc((size_t)H_D * H_D * 2);
    f16* d_w3t = (f16*)alloc((size_t)H_D * H_D * 2);
    f16* d_w4t = (f16*)alloc((size_t)X_D * H_D * 2);
    f16* a_w2t = (f16*)alloc((size_t)A_D * A_D * 2);
    f16* a_w3t = (f16*)alloc((size_t)Z_D * A_D * 2);
    f16* b_w2t = (f16*)alloc((size_t)A_D * A_D * 2);
    f16* b_w3t = (f16*)alloc((size_t)(Z_D * U_D) * A_D * 2);

    // ---- prep ----
    PrepArgs pa;
    const float* ws_[13] = {e_w1, e_w2, e_w3, d_w1, d_w2, d_w3, d_w4,
                            a_w1, a_w2, a_w3, b_w1, b_w2, b_w3};
    f16* wts_[13] = {W1t, e_w2t, e_w3t, d_w1t, d_w2t, d_w3t, d_w4t,
                     W1t + (size_t)1024 * X_D, a_w2t, a_w3t,
                     W1t + (size_t)1280 * X_D, b_w2t, b_w3t};
    int Ks_[13] = {X_D, H_D, H_D, Z_D, H_D, H_D, H_D, X_D, A_D, A_D, X_D, A_D, A_D};
    int Ns_[13] = {H_D, H_D, Z_D, H_D, H_D, H_D, X_D, A_D, A_D, Z_D, A_D, A_D, Z_D*U_D};
    int ntrans = 0;
    for (int i = 0; i < 13; ++i) {
        pa.w[i] = ws_[i]; pa.wt[i] = wts_[i]; pa.K[i] = Ks_[i]; pa.N[i] = Ns_[i];
        ntrans += (Ks_[i] >> 5) * (Ns_[i] >> 5);
    }
    pa.bsrc[0] = e_b1; pa.bsrc[1] = a_b1; pa.bsrc[2] = b_b1;
    pa.bias1 = bias1; pa.x = x; pa.xb = xb;
    const int ncvt = (B_SZ * X_D) / 1024;
    prep_k<<<ntrans + ncvt + 6, 256, 0, stream>>>(pa, ntrans, ncvt);

    auto G = [](const f16* A, const f16* W, const float* bias, void* C,
                int lda, int ldc, int K) {
        GArg g; g.A = A; g.W = W; g.bias = bias; g.C = C;
        g.lda = lda; g.ldc = ldc; g.K = K; return g;
    };
    GSet s;

    // ---- fused layer-1: [B,64] @ [64,1536] -> cc1 ----
    s.g[0] = G(xb, W1t, bias1, cc1, X_D, 1536, X_D);
    s.yn0 = 12; s.yn1 = 0;
    gemm_k<128,128,64,2,2,true,1><<<dim3(B_SZ/128, 12), 256, 0, stream>>>(s);

    // ---- merged layer-2: e2 (8 tiles) + a2 (2) + b2 (2), one launch ----
    s.g[0] = G(cc1,        e_w2t, e_b2, cc2,        1536, 1536, H_D);
    s.g[1] = G(cc1 + 1024, a_w2t, a_b2, cc2 + 1024, 1536, 1536, A_D);
    s.g[2] = G(cc1 + 1280, b_w2t, b_b2, cc2 + 1280, 1536, 1536, A_D);
    s.yn0 = 8; s.yn1 = 2;
    gemm_k<128,128,64,2,2,true,1><<<dim3(B_SZ/128, 12), 256, 0, stream>>>(s);

    // ---- fused middle: e3+a3+b3+Bu+Koopman -> znb ----
    mid_k<<<B_SZ/32, 256, 0, stream>>>(cc2, e_w3t, e_b3, a_w3t, a_b3,
                                       b_w3t, b_b3, u, znb);

    // ---- decoder ----
    s.yn0 = 8; s.yn1 = 0;
    s.g[0] = G(znb, d_w1t, d_b1, h1d, Z_D, H_D, Z_D);
    gemm_k<128,128,32,2,2,true,1><<<dim3(B_SZ/128, 8), 256, 0, stream>>>(s);

    s.g[0] = G(h1d, d_w2t, d_b2, h2d, H_D, H_D, H_D);
    gemm_k<128,128,64,2,2,true,1><<<dim3(B_SZ/128, 8), 256, 0, stream>>>(s);

    s.g[0] = G(h2d, d_w3t, d_b3, h3d, H_D, H_D, H_D);
    gemm_k<128,128,64,2,2,true,1><<<dim3(B_SZ/128, 8), 256, 0, stream>>>(s);

    s.g[0] = G(h3d, d_w4t, d_b4, d_out, H_D, X_D, H_D);
    s.yn0 = 1;
    gemm_k<64,64,64,2,2,false,0><<<dim3(B_SZ/64, 1), 256, 0, stream>>>(s);
}